// Round 9
// baseline (330.776 us; speedup 1.0000x reference)
//
#include <hip/hip_runtime.h>
#include <hip/hip_bf16.h>

// Problem constants (match reference file)
constexpr int K    = 8192;
constexpr int N4   = 6144;    // int4 rows
constexpr int N8   = 2048;    // uint8 rows
constexpr int NT   = N4 + N8; // 8192 output columns
constexpr int NG   = K / 128; // 64 groups per int4 row
constexpr int KS   = 4096;    // K per split (split-K x2)

typedef short  short8  __attribute__((ext_vector_type(8)));
typedef float  floatx4 __attribute__((ext_vector_type(4)));
typedef int    intx4   __attribute__((ext_vector_type(4)));  // clang vector:
// __builtin_nontemporal_load accepts this (HIP's int4 struct is rejected).

__device__ inline short f2bf(float f) {
    __hip_bfloat16 h = __float2bfloat16(f);   // RNE
    return __builtin_bit_cast(short, h);
}

// ---------------------------------------------------------------------------
// Prep: x2bf = bf16(x/awq) stored in MFMA A-fragment order:
//   x2bf[c*512 + lane*8 + j] = X[m = lane&15][k = c*32 + (lane>>4)*8 + j]
// Also: fwd = inverse of inv_perm, and out pre-filled with bias (the GEMV
// kernel accumulates into out with atomics; bias folds in for free here).
// ---------------------------------------------------------------------------
__global__ void prep_kernel(const float* __restrict__ x,
                            const float* __restrict__ awq,
                            const int*   __restrict__ inv_perm,
                            const float* __restrict__ bias,
                            short* __restrict__ x2bf,
                            int*   __restrict__ fwd,
                            float* __restrict__ out) {
    const int tid  = blockIdx.x * blockDim.x + threadIdx.x;   // 0..131071
    const int c    = tid >> 9;
    const int rem  = tid & 511;
    const int lane = rem >> 3;
    const int j    = rem & 7;
    const int m    = lane & 15;
    const int k    = c * 32 + (lane >> 4) * 8 + j;
    x2bf[tid] = f2bf(x[m * K + k] / awq[k]);
    if (tid < NT) fwd[inv_perm[tid]] = tid;
    out[tid] = bias[tid & (NT - 1)];          // out = bias, pre-perm indexed
}

// ---------------------------------------------------------------------------
// Split-K x2 MFMA GEMV, 32-ROW TILES (vs 16 in rounds 0-8): each x fragment
// feeds TWO B-fragments (rows 0-15 and 16-31) -> x re-read traffic halves
// (134 -> 67 MB). Theory being tested: total vmem reads (weights 268 MB +
// x) transit a shared per-CU return path whose measured service ceiling is
// ~4.3 TB/s (rounds 0/3/4/6/8 structural invariance); cutting read bytes is
// the only lever left. Weight loads stay NON-TEMPORAL (round-8: +7%).
//   int4 rows : wf = w*s - 8s      (group scale s per 128 k)
//   uint8 rows: wf = w - 128       (exact in bf16; s8 applied in epilogue;
//               algebraic merge of hi/lo nibbles + 8*s*sum_x correction)
// Block = 4 waves = one 32-row tile x half of K; wave w covers k in
// [split*4096 + w*1024, +1024) as 16 groups of 2 chunks. 2-stage A/B
// register pipeline (10 loads in flight per stage), sched_barrier pins.
// Loose launch_bounds: round-1 showed a tight VGPR cap collapses the
// pipeline; ~125 VGPR needed, occupancy is NOT the limiter (TLP-invariance
// proven rounds 0/1/3).
// Epilogue: 8KB LDS cross-wave reduce + s8/perm + atomicAdd (bias seeded).
// ---------------------------------------------------------------------------
__global__ __launch_bounds__(256)
void qgemv_kernel(const short* __restrict__ xf,
                  const int*   __restrict__ w4,
                  const float* __restrict__ s4,
                  const int*   __restrict__ w8,
                  const float* __restrict__ s8,
                  const int*   __restrict__ fwd,
                  float* __restrict__ out) {
    __shared__ float lds[4 * 512];

    const int t     = threadIdx.x;
    const int lane  = t & 63;
    const int w     = t >> 6;              // wave 0..3
    const int tile  = blockIdx.x >> 1;     // 0..255 (32-row tiles)
    const int split = blockIdx.x & 1;
    const int nb    = tile * 32;           // tile base row
    const int i     = lane & 15;
    const int q     = lane >> 4;
    const int rlo   = nb + i;              // rows 0-15 of tile
    const int rhi   = nb + 16 + i;         // rows 16-31 of tile

    const bool is4  = (nb < N4);           // N4 % 32 == 0: tiles homogeneous
    const int kbase = split * KS + w * 1024;
    const int* wplo = (is4 ? (w4 + (size_t)rlo * K)
                           : (w8 + (size_t)(rlo - N4) * K)) + kbase + q * 8;
    const int* wphi = (is4 ? (w4 + (size_t)rhi * K)
                           : (w8 + (size_t)(rhi - N4) * K)) + kbase + q * 8;
    const short* xw = xf + (size_t)(kbase >> 5) * 512 + lane * 8; // + chunk*512
    const float* splo = is4 ? (s4 + (size_t)rlo * NG + (kbase >> 7)) : nullptr;
    const float* sphi = is4 ? (s4 + (size_t)rhi * NG + (kbase >> 7)) : nullptr;

    floatx4 accL = {0.f, 0.f, 0.f, 0.f};
    floatx4 accH = {0.f, 0.f, 0.f, 0.f};

    // group = 2 chunks = 64 k. Buffer: per chunk {lo16B, lo16B, hi16B, hi16B}.
    intx4  wbA[8], wbB[8];
    short8 xA[2], xB[2];
    float  sLA = 0.f, sHA = 0.f, sLB = 0.f, sHB = 0.f;

    auto loadg = [&](int g, intx4* wb, short8* xv, float& sL, float& sH) {
        #pragma unroll
        for (int c = 0; c < 2; ++c) {
            const size_t co = (size_t)(g * 2 + c);
            wb[4 * c]     = __builtin_nontemporal_load((const intx4*)(wplo + co * 32));
            wb[4 * c + 1] = __builtin_nontemporal_load((const intx4*)(wplo + co * 32 + 4));
            wb[4 * c + 2] = __builtin_nontemporal_load((const intx4*)(wphi + co * 32));
            wb[4 * c + 3] = __builtin_nontemporal_load((const intx4*)(wphi + co * 32 + 4));
            xv[c]         = *(const short8*)(xw + co * 512);
        }
        if (is4) { sL = splo[g >> 1]; sH = sphi[g >> 1]; }  // 1 scale per 128k
    };

    auto dq8 = [&](const intx4& a, const intx4& z, float sc, float sb) {
        short8 bf;
        bf[0] = f2bf((float)a[0] * sc + sb);
        bf[1] = f2bf((float)a[1] * sc + sb);
        bf[2] = f2bf((float)a[2] * sc + sb);
        bf[3] = f2bf((float)a[3] * sc + sb);
        bf[4] = f2bf((float)z[0] * sc + sb);
        bf[5] = f2bf((float)z[1] * sc + sb);
        bf[6] = f2bf((float)z[2] * sc + sb);
        bf[7] = f2bf((float)z[3] * sc + sb);
        return bf;
    };

    auto compg = [&](const intx4* wb, const short8* xv, float sL, float sH) {
        const float scL = is4 ? sL : 1.f, sbL = is4 ? -8.f * sL : -128.f;
        const float scH = is4 ? sH : 1.f, sbH = is4 ? -8.f * sH : -128.f;
        #pragma unroll
        for (int c = 0; c < 2; ++c) {
            const short8 bfL = dq8(wb[4 * c],     wb[4 * c + 1], scL, sbL);
            accL = __builtin_amdgcn_mfma_f32_16x16x32_bf16(xv[c], bfL, accL, 0, 0, 0);
            const short8 bfH = dq8(wb[4 * c + 2], wb[4 * c + 3], scH, sbH);
            accH = __builtin_amdgcn_mfma_f32_16x16x32_bf16(xv[c], bfH, accH, 0, 0, 0);
        }
    };

    // 16 groups, 2-stage manual pipeline (A/B buffers), peeled tail.
    loadg(0, wbA, xA, sLA, sHA);
    __builtin_amdgcn_sched_barrier(0);
    #pragma unroll 1
    for (int g = 0; g < 14; g += 2) {
        loadg(g + 1, wbB, xB, sLB, sHB);
        __builtin_amdgcn_sched_barrier(0);
        compg(wbA, xA, sLA, sHA);         // group g
        loadg(g + 2, wbA, xA, sLA, sHA);
        __builtin_amdgcn_sched_barrier(0);
        compg(wbB, xB, sLB, sHB);         // group g+1
    }
    loadg(15, wbB, xB, sLB, sHB);
    __builtin_amdgcn_sched_barrier(0);
    compg(wbA, xA, sLA, sHA);             // group 14
    compg(wbB, xB, sLB, sHB);             // group 15

    // ---- cross-wave reduce + fused scale/perm atomic writeout ----
    #pragma unroll
    for (int r = 0; r < 4; ++r) {
        lds[w * 512 +       (q * 4 + r) * 16 + i] = accL[r];
        lds[w * 512 + 256 + (q * 4 + r) * 16 + i] = accH[r];
    }
    __syncthreads();

    {
        const int m  = t >> 4;     // 0..15 (batch row)
        const int i2 = t & 15;     // 0..15 (col within half-tile)
        #pragma unroll
        for (int h = 0; h < 2; ++h) {          // lo / hi half of the tile
            const float v = lds[0 * 512 + h * 256 + t] + lds[1 * 512 + h * 256 + t]
                          + lds[2 * 512 + h * 256 + t] + lds[3 * 512 + h * 256 + t];
            const int n  = nb + h * 16 + i2;
            const float sc = is4 ? 1.f : s8[n - N4];
            const int d  = fwd[n];
            atomicAdd(&out[(size_t)m * NT + d], v * sc);
        }
    }
}

// ---------------------------------------------------------------------------
extern "C" void kernel_launch(void* const* d_in, const int* in_sizes, int n_in,
                              void* d_out, int out_size, void* d_ws, size_t ws_size,
                              hipStream_t stream) {
    const float* x        = (const float*)d_in[0];
    const int*   w_int4   = (const int*)  d_in[1];
    const float* s_int4   = (const float*)d_in[2];
    const int*   w_uint8  = (const int*)  d_in[3];
    const float* s_int8   = (const float*)d_in[4];
    const float* awq      = (const float*)d_in[5];
    const float* bias     = (const float*)d_in[6];
    const int*   inv_perm = (const int*)  d_in[7];
    // d_in[8] = group_size (==128), compile-time constant here

    short* x2bf = (short*)d_ws;                                       // 256 KB
    int*   fwd  = (int*)((char*)d_ws + (size_t)16 * K * sizeof(short)); // 32 KB

    prep_kernel<<<(16 * K) / 256, 256, 0, stream>>>(x, awq, inv_perm, bias,
                                                    x2bf, fwd, (float*)d_out);
    qgemv_kernel<<<(NT / 32) * 2, 256, 0, stream>>>(x2bf, w_int4, s_int4,
                                                    w_uint8, s_int8, fwd,
                                                    (float*)d_out);
}